// Round 4
// baseline (396.811 us; speedup 1.0000x reference)
//
#include <hip/hip_runtime.h>

#define NB 256          // histogram bins
#define NCH 48          // B*C = 16*3
#define HW (1024*1024)  // elements per channel
#define BLOCKS_PER_CH 64
#define THREADS 256
#define NWAVE (THREADS / 64)

__device__ __forceinline__ int quant255(float v) {
    v = fminf(fmaxf(v, 0.0f), 1.0f);
    int q = (int)(v * 255.0f);     // fp32 mul + trunc, same as jnp
    q = q < 0 ? 0 : q;
    q = q > 255 ? 255 : q;
    return q;
}

// ---- Kernel 1: quantize to packed u8 (cached in ws) + per-channel hist ----
// Per-wave replicated LDS histograms: zero inter-wave same-address atomic
// contention; intra-wave random bins over 32 banks avg ~2-way (free, m136).
__global__ __launch_bounds__(THREADS) void hist_quant_kernel(
    const float* __restrict__ x, unsigned int* __restrict__ ghist,
    unsigned int* __restrict__ q) {
    __shared__ unsigned int lh[NWAVE][NB];
    const int t = threadIdx.x;
    const int w = t >> 6;
    for (int i = t; i < NWAVE * NB; i += THREADS)
        ((unsigned int*)lh)[i] = 0u;
    __syncthreads();

    const int ch  = blockIdx.x / BLOCKS_PER_CH;
    const int blk = blockIdx.x % BLOCKS_PER_CH;

    const float4* xp = (const float4*)(x + (size_t)ch * HW);
    unsigned int* qp = q + (size_t)ch * (HW / 4);
    const int n4 = (HW / 4) / BLOCKS_PER_CH;   // 4096
    const int base = blk * n4;

    for (int i = base + t; i < base + n4; i += THREADS) {
        float4 v = xp[i];
        int q0 = quant255(v.x), q1 = quant255(v.y);
        int q2 = quant255(v.z), q3 = quant255(v.w);
        atomicAdd(&lh[w][q0], 1u);
        atomicAdd(&lh[w][q1], 1u);
        atomicAdd(&lh[w][q2], 1u);
        atomicAdd(&lh[w][q3], 1u);
        qp[i] = (unsigned)q0 | ((unsigned)q1 << 8)
              | ((unsigned)q2 << 16) | ((unsigned)q3 << 24);
    }
    __syncthreads();
    unsigned int s = lh[0][t] + lh[1][t] + lh[2][t] + lh[3][t];
    if (s != 0u)
        atomicAdd(&ghist[ch * NB + t], s);
}

// ---- Kernel 2: fused CDF build (per-block, redundant-but-cheap) + remap ----
__global__ __launch_bounds__(THREADS) void cdf_remap_kernel(
    const unsigned int* __restrict__ q, const unsigned int* __restrict__ ghist,
    float* __restrict__ y) {
    __shared__ float sbuf[NB];
    __shared__ float lc[NB];
    const int t = threadIdx.x;
    const int ch  = blockIdx.x / BLOCKS_PER_CH;
    const int blk = blockIdx.x % BLOCKS_PER_CH;

    // Hillis-Steele inclusive scan; partials are integers < 2^24 -> exact fp32
    sbuf[t] = (float)ghist[ch * NB + t];
    __syncthreads();
    for (int off = 1; off < NB; off <<= 1) {
        float add = (t >= off) ? sbuf[t - off] : 0.0f;
        __syncthreads();
        sbuf[t] += add;
        __syncthreads();
    }
    float total = sbuf[NB - 1];
    lc[t] = sbuf[t] / fmaxf(total, 1.0f);
    __syncthreads();

    // Remap: read 16 packed pixels per uint4 load, write 4 float4s
    const uint4* qp = (const uint4*)(q + (size_t)ch * (HW / 4));
    float4*      yp = (float4*)(y + (size_t)ch * HW);
    const int n16 = (HW / 16) / BLOCKS_PER_CH;   // 1024 uint4s per block
    const int base = blk * n16;

    for (int i = base + t; i < base + n16; i += THREADS) {
        uint4 pv = qp[i];
        const unsigned pk[4] = { pv.x, pv.y, pv.z, pv.w };
        #pragma unroll
        for (int j = 0; j < 4; ++j) {
            unsigned p = pk[j];
            float4 o = make_float4(lc[p & 255], lc[(p >> 8) & 255],
                                   lc[(p >> 16) & 255], lc[p >> 24]);
            yp[i * 4 + j] = o;
        }
    }
}

extern "C" void kernel_launch(void* const* d_in, const int* in_sizes, int n_in,
                              void* d_out, int out_size, void* d_ws, size_t ws_size,
                              hipStream_t stream) {
    const float* x = (const float*)d_in[0];
    float* y = (float*)d_out;

    unsigned int* ghist = (unsigned int*)d_ws;
    unsigned int* q     = (unsigned int*)((char*)d_ws + 256 * 1024); // 48 MB packed-u8 region

    // ws is poisoned to 0xAA before every launch -> zero the histogram region
    hipMemsetAsync(ghist, 0, NCH * NB * sizeof(unsigned int), stream);

    hist_quant_kernel<<<NCH * BLOCKS_PER_CH, THREADS, 0, stream>>>(x, ghist, q);
    cdf_remap_kernel <<<NCH * BLOCKS_PER_CH, THREADS, 0, stream>>>(q, ghist, y);
}

// Round 5
// 368.271 us; speedup vs baseline: 1.0775x; 1.0775x over previous
//
#include <hip/hip_runtime.h>

#define NB 256              // histogram bins
#define NCH 48              // B*C = 16*3
#define HW (1024*1024)      // elements per channel
#define WPC (HW / 4)        // packed words per channel = 262144
#define BPC 32              // fused-path blocks per channel
#define GRID (NCH * BPC)    // 1536 -> needs 6 blocks/CU co-resident
#define THREADS 256
#define KTOT 32             // packed words per thread
#define KLDS 6              // first 6 words live in LDS (6 KB/block)
#define KREG (KTOT - KLDS)  // remaining 26 words live in registers
#define FB_BPC 64           // fallback blocks per channel

__device__ __forceinline__ int quant255(float v) {
    v = fminf(fmaxf(v, 0.0f), 1.0f);
    int q = (int)(v * 255.0f);     // fp32 mul + trunc, same as jnp
    q = q < 0 ? 0 : q;
    q = q > 255 ? 255 : q;
    return q;
}

__device__ __forceinline__ unsigned quant_pack(float4 v, unsigned* lh, int w) {
    int q0 = quant255(v.x), q1 = quant255(v.y);
    int q2 = quant255(v.z), q3 = quant255(v.w);
    atomicAdd(&lh[w * NB + q0], 1u);
    atomicAdd(&lh[w * NB + q1], 1u);
    atomicAdd(&lh[w * NB + q2], 1u);
    atomicAdd(&lh[w * NB + q3], 1u);
    return (unsigned)q0 | ((unsigned)q1 << 8)
         | ((unsigned)q2 << 16) | ((unsigned)q3 << 24);
}

// ---------------- Fused single-pass kernel (software grid barrier) --------
// LDS: 6 KB packed q + 4 KB hist = 10240 B -> 6 blocks/CU under both 64 KB
// and 160 KB per-CU LDS models. VGPR capped at 85 by launch_bounds(256,6)
// -> 6 waves/EU. Host only launches this if the occupancy query confirms
// >= 6 blocks/CU, so all 1536 blocks are co-resident and the barrier is
// deadlock-free.
__global__ __launch_bounds__(THREADS, 6) void fused_he_kernel(
    const float* __restrict__ x, unsigned int* __restrict__ ghist,
    unsigned int* __restrict__ bar, float* __restrict__ y) {
    __shared__ unsigned int sq[KLDS * THREADS];   // 6 KB packed q
    __shared__ unsigned int lh[4 * NB];           // 4 KB hist; reused for scan/LUT

    const int t  = threadIdx.x;
    const int w  = t >> 6;
    const int ch  = blockIdx.x / BPC;
    const int blk = blockIdx.x % BPC;

    for (int i = t; i < 4 * NB; i += THREADS) lh[i] = 0u;
    __syncthreads();

    const float4* xp = (const float4*)x + (size_t)ch * WPC
                       + (size_t)blk * (KTOT * THREADS);

    // Phase 1a: first KLDS words -> LDS (runtime loop, low reg pressure)
    for (int k = 0; k < KLDS; ++k) {
        float4 v = xp[k * THREADS + t];
        sq[k * THREADS + t] = quant_pack(v, lh, w);
    }
    // Phase 1b: remaining words -> registers (must fully unroll: const idx)
    unsigned int qpk[KREG];
    #pragma unroll
    for (int k = 0; k < KREG; ++k) {
        float4 v = xp[(KLDS + k) * THREADS + t];
        qpk[k] = quant_pack(v, lh, w);
    }
    __syncthreads();

    // Block hist -> global (one atomic per bin per block)
    unsigned int s = lh[t] + lh[NB + t] + lh[2 * NB + t] + lh[3 * NB + t];
    atomicAdd(&ghist[ch * NB + t], s);
    __threadfence();
    __syncthreads();

    // Software grid barrier (co-residency guaranteed by host-side occ gate)
    if (t == 0) {
        atomicAdd(bar, 1u);
        while (atomicAdd(bar, 0u) < (unsigned)GRID)
            __builtin_amdgcn_s_sleep(8);
    }
    __syncthreads();

    // Phase 2: CDF scan in LDS (aliased onto dead hist array).
    // Partials are integers < 2^24 -> exact fp32. Coherent ghist read via
    // atomicAdd(,0) (device-scope, immune to stale L1/L2).
    float* sbuf = (float*)lh;        // lh[0..255]
    float* lut  = (float*)lh + NB;   // lh[256..511]
    sbuf[t] = (float)atomicAdd(&ghist[ch * NB + t], 0u);
    __syncthreads();
    for (int off = 1; off < NB; off <<= 1) {
        float add = (t >= off) ? sbuf[t - off] : 0.0f;
        __syncthreads();
        sbuf[t] += add;
        __syncthreads();
    }
    float total = sbuf[NB - 1];
    lut[t] = sbuf[t] / fmaxf(total, 1.0f);
    __syncthreads();

    // Phase 3: remap; lane-contiguous float4 stores
    float4* yp = (float4*)y + (size_t)ch * WPC + (size_t)blk * (KTOT * THREADS);
    for (int k = 0; k < KLDS; ++k) {
        unsigned p = sq[k * THREADS + t];
        yp[k * THREADS + t] = make_float4(lut[p & 255], lut[(p >> 8) & 255],
                                          lut[(p >> 16) & 255], lut[p >> 24]);
    }
    #pragma unroll
    for (int k = 0; k < KREG; ++k) {
        unsigned p = qpk[k];
        yp[(KLDS + k) * THREADS + t] = make_float4(lut[p & 255], lut[(p >> 8) & 255],
                                                   lut[(p >> 16) & 255], lut[p >> 24]);
    }
}

// ---------------- Fallback path (proven R2 structure) ----------------
__global__ __launch_bounds__(THREADS) void hist_quant_kernel(
    const float* __restrict__ x, unsigned int* __restrict__ ghist,
    unsigned int* __restrict__ q) {
    __shared__ unsigned int lh[4 * NB];
    const int t = threadIdx.x;
    const int w = t >> 6;
    for (int i = t; i < 4 * NB; i += THREADS) lh[i] = 0u;
    __syncthreads();

    const int ch  = blockIdx.x / FB_BPC;
    const int blk = blockIdx.x % FB_BPC;
    const float4* xp = (const float4*)(x + (size_t)ch * HW);
    unsigned int* qp = q + (size_t)ch * WPC;
    const int n4 = WPC / FB_BPC;
    const int base = blk * n4;

    for (int i = base + t; i < base + n4; i += THREADS) {
        float4 v = xp[i];
        qp[i] = quant_pack(v, lh, w);
    }
    __syncthreads();
    unsigned int s = lh[t] + lh[NB + t] + lh[2 * NB + t] + lh[3 * NB + t];
    if (s) atomicAdd(&ghist[ch * NB + t], s);
}

__global__ __launch_bounds__(THREADS) void cdf_remap_kernel(
    const unsigned int* __restrict__ q, const unsigned int* __restrict__ ghist,
    float* __restrict__ y) {
    __shared__ float sbuf[NB];
    __shared__ float lut[NB];
    const int t = threadIdx.x;
    const int ch  = blockIdx.x / FB_BPC;
    const int blk = blockIdx.x % FB_BPC;

    sbuf[t] = (float)ghist[ch * NB + t];
    __syncthreads();
    for (int off = 1; off < NB; off <<= 1) {
        float add = (t >= off) ? sbuf[t - off] : 0.0f;
        __syncthreads();
        sbuf[t] += add;
        __syncthreads();
    }
    float total = sbuf[NB - 1];
    lut[t] = sbuf[t] / fmaxf(total, 1.0f);
    __syncthreads();

    // lane-contiguous: 4 B packed read + 16 B float4 write per thread
    const unsigned int* qp = q + (size_t)ch * WPC;
    float4*             yp = (float4*)(y + (size_t)ch * HW);
    const int n4 = WPC / FB_BPC;
    const int base = blk * n4;
    for (int i = base + t; i < base + n4; i += THREADS) {
        unsigned p = qp[i];
        yp[i] = make_float4(lut[p & 255], lut[(p >> 8) & 255],
                            lut[(p >> 16) & 255], lut[p >> 24]);
    }
}

extern "C" void kernel_launch(void* const* d_in, const int* in_sizes, int n_in,
                              void* d_out, int out_size, void* d_ws, size_t ws_size,
                              hipStream_t stream) {
    const float* x = (const float*)d_in[0];
    float* y = (float*)d_out;

    unsigned int* ghist = (unsigned int*)d_ws;                           // 48 KB
    unsigned int* bar   = (unsigned int*)((char*)d_ws + 60 * 1024);      // 4 B
    unsigned int* q     = (unsigned int*)((char*)d_ws + 256 * 1024);     // 48 MB (fallback)

    // zero ghist + barrier counter (ws is 0xAA-poisoned before every launch)
    hipMemsetAsync(d_ws, 0, 64 * 1024, stream);

    // Host-side occupancy gate (capture-safe: pure query, no stream ops).
    // Fused path requires all 1536 blocks co-resident: >= 6 blocks/CU.
    int occ = 0;
    hipError_t qe = hipOccupancyMaxActiveBlocksPerMultiprocessor(
        &occ, fused_he_kernel, THREADS, 0);
    bool fused_ok = (qe == hipSuccess) && (occ >= GRID / 256);

    if (fused_ok) {
        fused_he_kernel<<<GRID, THREADS, 0, stream>>>(x, ghist, bar, y);
    } else {
        hist_quant_kernel<<<NCH * FB_BPC, THREADS, 0, stream>>>(x, ghist, q);
        cdf_remap_kernel <<<NCH * FB_BPC, THREADS, 0, stream>>>(q, ghist, y);
    }
}